// Round 11
// baseline (248.460 us; speedup 1.0000x reference)
//
#include <hip/hip_runtime.h>
#include <hip/hip_fp16.h>
#include <hip/hip_bf16.h>
#include <math.h>

typedef __attribute__((ext_vector_type(8))) short bf16x8;
typedef __attribute__((ext_vector_type(4))) float f32x4;

__device__ __forceinline__ unsigned short f2bf(float x) {
    union { float f; unsigned u; } v; v.f = x;
    unsigned r = v.u + 0x7FFFu + ((v.u >> 16) & 1u);   // RNE
    return (unsigned short)(r >> 16);
}
__device__ __forceinline__ unsigned short f2h(float x) {
    union { __half h; unsigned short u; } v; v.h = __float2half(x); return v.u;
}
__device__ __forceinline__ float h2f(unsigned short u) {
    union { __half h; unsigned short u; } v; v.u = u; return __half2float(v.h);
}
// pack 8 fp32 -> bf16x8 (RNE, HW packed cvt)
__device__ __forceinline__ bf16x8 pack8(const float* p) {
    union { bf16x8 v; __hip_bfloat162 b[4]; } u;
    #pragma unroll
    for (int i = 0; i < 4; ++i)
        u.b[i] = __float22bfloat162_rn(make_float2(p[2 * i], p[2 * i + 1]));
    return u.v;
}

// XCD-aware tile decode (R4-verified).
template<bool M_INNER>
__device__ __forceinline__ void tile_decode(int id, int NT, int MT, int ML,
                                            int& m, int& n, int& zz)
{
    const int xcd = id & 7;
    const int s = id >> 3;
    int mloc;
    if (M_INNER) { mloc = s % ML; n = s / ML; }
    else         { n = s % NT;   mloc = s / NT; }
    const int g = xcd * ML + mloc;
    m = g % MT;
    zz = g / MT;
}

// Async global->LDS staging of a ROWSx64 bf16 tile, 16B DMA, XOR-swizzled.
template<int ROWS>
__device__ __forceinline__ void stage64(const unsigned short* g, long lda,
                                        unsigned short* lds, int wave, int lane)
{
    const int rr = lane >> 3, cc = lane & 7;
    const int ccg = (cc ^ rr) * 8;
    #pragma unroll
    for (int s = 0; s < ROWS / 32; ++s) {
        const int seg = wave * (ROWS / 32) + s;
        const unsigned short* gp = g + (long)(seg * 8 + rr) * lda + ccg;
        __builtin_amdgcn_global_load_lds(
            (const __attribute__((address_space(1))) void*)gp,
            (__attribute__((address_space(3))) void*)(lds + seg * 512),
            16, 0, 0);
    }
}

// ---------------------------------------------------------------------------
// 4 weights [512][512] fp32 -> transposed bf16, one dispatch.
struct WT4Args {
    const float* src[4];
    unsigned short* dh[4];
};
__global__ __launch_bounds__(256)
void wtrans4(WT4Args a)
{
    __shared__ float T[32][33];
    const int z = blockIdx.z;
    const int Cc = 512, R = 512;
    const float* s = a.src[z];
    const int r0 = blockIdx.y * 32, c0 = blockIdx.x * 32;
    const int t = threadIdx.x;
    {
        const int r = t >> 3, cq = (t & 7) * 4;
        float4 v = *(const float4*)(s + (long)(r0 + r) * Cc + c0 + cq);
        T[r][cq] = v.x; T[r][cq + 1] = v.y; T[r][cq + 2] = v.z; T[r][cq + 3] = v.w;
    }
    __syncthreads();
    {
        const int c = t >> 3, rq = (t & 7) * 4;
        ushort4 h;
        h.x = f2bf(T[rq][c]); h.y = f2bf(T[rq + 1][c]);
        h.z = f2bf(T[rq + 2][c]); h.w = f2bf(T[rq + 3][c]);
        *(ushort4*)(a.dh[z] + (long)(c0 + c) * R + r0 + rq) = h;
    }
}

// ---------------------------------------------------------------------------
// Merged Q/K/V projection — REGISTER-DIRECT: no LDS, no barriers.
// MFMA A/B fragment layout (row=lane&15, k=quad*8+j) maps directly to
// row-major global addresses -> per-lane 8-elem contiguous loads. A is fp32
// (converted in-VGPR), B is bf16 WT. k+32 prefetched during the MFMAs; no
// __syncthreads -> no vmcnt(0) drain anywhere in the loop.
// 128x128 block (4 waves 2x2, each 64x64). 768 blocks, n-inner decode.
struct ProjArgs {
    const float* Af[3];
    const unsigned short* Bh[3];
    const float* bias[3];
    unsigned short* Ch[3];
};
__global__ __launch_bounds__(256)
void proj_gemm(ProjArgs pa)
{
    int mt, nt, z;
    tile_decode<false>(blockIdx.x, 4, 64, 24, mt, nt, z);

    const float* Af = pa.Af[z];
    const unsigned short* Bh = pa.Bh[z];
    const float* bias = pa.bias[z];

    const int tid = threadIdx.x;
    const int m0 = mt * 128, n0 = nt * 128;
    const int wave = tid >> 6, lane = tid & 63;
    const int wr = wave >> 1, wc = wave & 1;
    const int quad = lane >> 4, mr = lane & 15;

    const float* aptr[4];
    const unsigned short* bptr[4];
    #pragma unroll
    for (int r = 0; r < 4; ++r)
        aptr[r] = Af + (long)(m0 + wr * 64 + r * 16 + mr) * 512 + quad * 8;
    #pragma unroll
    for (int c = 0; c < 4; ++c)
        bptr[c] = Bh + (long)(n0 + wc * 64 + c * 16 + mr) * 512 + quad * 8;

    f32x4 acc[4][4] = {};

    float4 a0[4], a1[4];
    bf16x8 bv[4];
    #pragma unroll
    for (int r = 0; r < 4; ++r) {
        a0[r] = *(const float4*)(aptr[r]);
        a1[r] = *(const float4*)(aptr[r] + 4);
    }
    #pragma unroll
    for (int c = 0; c < 4; ++c)
        bv[c] = *(const bf16x8*)(bptr[c]);

    for (int k0 = 0; k0 < 512; k0 += 32) {
        bf16x8 af[4], bf[4];
        #pragma unroll
        for (int r = 0; r < 4; ++r) {
            float t[8] = { a0[r].x, a0[r].y, a0[r].z, a0[r].w,
                           a1[r].x, a1[r].y, a1[r].z, a1[r].w };
            af[r] = pack8(t);
        }
        #pragma unroll
        for (int c = 0; c < 4; ++c) bf[c] = bv[c];

        if (k0 + 32 < 512) {
            #pragma unroll
            for (int r = 0; r < 4; ++r) {
                a0[r] = *(const float4*)(aptr[r] + k0 + 32);
                a1[r] = *(const float4*)(aptr[r] + k0 + 36);
            }
            #pragma unroll
            for (int c = 0; c < 4; ++c)
                bv[c] = *(const bf16x8*)(bptr[c] + k0 + 32);
        }

        #pragma unroll
        for (int r = 0; r < 4; ++r)
            #pragma unroll
            for (int c = 0; c < 4; ++c)
                acc[r][c] = __builtin_amdgcn_mfma_f32_16x16x32_bf16(af[r], bf[c], acc[r][c], 0, 0, 0);
    }

    if (z < 2) {
        unsigned short* Chi = pa.Ch[z];
        #pragma unroll
        for (int r = 0; r < 4; ++r)
            #pragma unroll
            for (int c = 0; c < 4; ++c) {
                const int col = n0 + wc * 64 + c * 16 + mr;
                const float bv2 = bias[col];
                #pragma unroll
                for (int e = 0; e < 4; ++e) {
                    const int rowg = m0 + wr * 64 + r * 16 + quad * 4 + e;
                    Chi[(long)rowg * 512 + col] = f2bf(acc[r][c][e] + bv2);
                }
            }
    } else {
        // transposed: VT[b][col][l]; C/D layout's 4 consecutive rows -> ushort4
        unsigned short* VTh = pa.Ch[2];
        #pragma unroll
        for (int r = 0; r < 4; ++r)
            #pragma unroll
            for (int c = 0; c < 4; ++c) {
                const int col = n0 + wc * 64 + c * 16 + mr;
                const float bv2 = bias[col];
                const int rowg0 = m0 + wr * 64 + r * 16 + quad * 4;
                const int b = rowg0 >> 11, l0 = rowg0 & 2047;
                ushort4 hv;
                hv.x = f2bf(acc[r][c][0] + bv2);
                hv.y = f2bf(acc[r][c][1] + bv2);
                hv.z = f2bf(acc[r][c][2] + bv2);
                hv.w = f2bf(acc[r][c][3] + bv2);
                *(ushort4*)(VTh + (long)b * (512 * 2048) + (long)col * 2048 + l0) = hv;
            }
    }
}

// ---------------------------------------------------------------------------
// QK^T: S(fp16) = scale * Q @ K^T + per-tile softmax partials. (R7, proven)
union QKTSmem {
    unsigned short stage[2][128 * 64];
    unsigned short ep[128 * 132];
};
__global__ __launch_bounds__(256)
void qkt_gemm(const unsigned short* __restrict__ Qg, const unsigned short* __restrict__ Kg,
              unsigned short* __restrict__ Sg, float2* __restrict__ stats, float alpha)
{
    __shared__ __align__(16) QKTSmem sm;

    int mt, nt, zz;
    tile_decode<true>(blockIdx.x, 16, 16, 8, mt, nt, zz);

    const int tid = threadIdx.x;
    const int m0 = mt * 128, n0 = nt * 128;
    const long LC = 2048L * 512;
    const unsigned short* pA = Qg + (long)zz * LC + (long)m0 * 512;
    const unsigned short* pB = Kg + (long)zz * LC + (long)n0 * 512;

    const int wave = tid >> 6, lane = tid & 63;
    const int wr = wave >> 1, wc = wave & 1;
    const int quad = lane >> 4, mr = lane & 15;
    const int sw = mr & 7;

    f32x4 acc[4][4] = {};

    for (int k0 = 0; k0 < 512; k0 += 64) {
        stage64<128>(pA + k0, 512, sm.stage[0], wave, lane);
        stage64<128>(pB + k0, 512, sm.stage[1], wave, lane);
        __syncthreads();
        #pragma unroll
        for (int h = 0; h < 2; ++h) {
            const int q2 = (h << 2) | quad;
            bf16x8 af[4], bf[4];
            #pragma unroll
            for (int r = 0; r < 4; ++r)
                af[r] = *(const bf16x8*)&sm.stage[0][(wr * 64 + r * 16 + mr) * 64 + ((q2 ^ sw) << 3)];
            #pragma unroll
            for (int c = 0; c < 4; ++c)
                bf[c] = *(const bf16x8*)&sm.stage[1][(wc * 64 + c * 16 + mr) * 64 + ((q2 ^ sw) << 3)];
            #pragma unroll
            for (int r = 0; r < 4; ++r)
                #pragma unroll
                for (int c = 0; c < 4; ++c)
                    acc[r][c] = __builtin_amdgcn_mfma_f32_16x16x32_bf16(af[r], bf[c], acc[r][c], 0, 0, 0);
        }
        __syncthreads();
    }

    #pragma unroll
    for (int r = 0; r < 4; ++r)
        #pragma unroll
        for (int c = 0; c < 4; ++c) {
            const int col = wc * 64 + c * 16 + mr;
            #pragma unroll
            for (int e = 0; e < 4; ++e) {
                const int rowl = wr * 64 + r * 16 + quad * 4 + e;
                sm.ep[rowl * 132 + col] = f2h(acc[r][c][e] * alpha);
            }
        }
    __syncthreads();
    {
        const int R = tid >> 1, hh = tid & 1;
        const unsigned short* src = &sm.ep[R * 132 + hh * 64];
        unsigned short* dst = Sg + (long)zz * (2048L * 2048) + (long)(m0 + R) * 2048 + n0 + hh * 64;
        bf16x8 ch[8];
        #pragma unroll
        for (int j = 0; j < 8; ++j) {
            ch[j] = *(const bf16x8*)(src + j * 8);
            *(bf16x8*)(dst + j * 8) = ch[j];
        }
        float mloc = -1e30f;
        #pragma unroll
        for (int j = 0; j < 8; ++j)
            #pragma unroll
            for (int i = 0; i < 8; ++i)
                mloc = fmaxf(mloc, h2f((unsigned short)ch[j][i]));
        const float m2 = fmaxf(mloc, __shfl_xor(mloc, 1));
        float sl = 0.f;
        #pragma unroll
        for (int j = 0; j < 8; ++j)
            #pragma unroll
            for (int i = 0; i < 8; ++i)
                sl += __expf(h2f((unsigned short)ch[j][i]) - m2);
        sl += __shfl_xor(sl, 1);
        if (hh == 0)
            stats[((long)zz * 2048 + m0 + R) * 16 + nt] = make_float2(m2, sl);
    }
}

// ---------------------------------------------------------------------------
// PV, fused softmax finalization. 64x128 tile (R8 config, 512 blocks).
__global__ __launch_bounds__(256)
void pv_gemm(const unsigned short* __restrict__ Sg, const unsigned short* __restrict__ VTg,
             const float2* __restrict__ stats, unsigned short* __restrict__ Og)
{
    __shared__ __align__(16) unsigned short smA[64 * 64];
    __shared__ __align__(16) unsigned short smB[128 * 64];

    int mt, nt, zz;
    tile_decode<false>(blockIdx.x, 4, 32, 16, mt, nt, zz);

    const int tid = threadIdx.x;
    const int m0 = mt * 64, n0 = nt * 128;
    const long LL = 2048L * 2048, LC = 2048L * 512;
    const unsigned short* pS = Sg + (long)zz * LL + (long)m0 * 2048;
    const unsigned short* pB = VTg + (long)zz * LC + (long)n0 * 2048;

    const int wave = tid >> 6, lane = tid & 63;
    const int quad = lane >> 4, mr = lane & 15;
    const int sw = mr & 7;
    const int tr = tid >> 2, qt = tid & 3;
    const int swA = tr & 7;

    float m_row, inv_row;
    {
        const float2* st = stats + ((long)zz * 2048 + m0 + tr) * 16;
        float2 s[16];
        float m = -1e30f;
        #pragma unroll
        for (int i = 0; i < 16; ++i) { s[i] = st[i]; m = fmaxf(m, s[i].x); }
        float l = 0.f;
        #pragma unroll
        for (int i = 0; i < 16; ++i) l += s[i].y * __expf(s[i].x - m);
        m_row = m;
        inv_row = 1.0f / l;
    }

    f32x4 acc[4][2] = {};

    bf16x8 pre[2];
    {
        const unsigned short* s0 = pS + (long)tr * 2048 + qt * 16;
        pre[0] = *(const bf16x8*)(s0);
        pre[1] = *(const bf16x8*)(s0 + 8);
    }

    for (int k0 = 0; k0 < 2048; k0 += 64) {
        #pragma unroll
        for (int c2 = 0; c2 < 2; ++c2) {
            float t[8];
            #pragma unroll
            for (int i = 0; i < 8; ++i)
                t[i] = __expf(h2f((unsigned short)pre[c2][i]) - m_row) * inv_row;
            const int cc = qt * 2 + c2;
            *(bf16x8*)&smA[tr * 64 + ((cc ^ swA) << 3)] = pack8(t);
        }
        stage64<128>(pB + k0, 2048, smB, wave, lane);
        __syncthreads();

        if (k0 + 64 < 2048) {
            const unsigned short* s2 = pS + (long)tr * 2048 + (k0 + 64) + qt * 16;
            pre[0] = *(const bf16x8*)(s2);
            pre[1] = *(const bf16x8*)(s2 + 8);
        }

        #pragma unroll
        for (int h = 0; h < 2; ++h) {
            const int q2 = (h << 2) | quad;
            bf16x8 af[4], bf[2];
            #pragma unroll
            for (int r = 0; r < 4; ++r)
                af[r] = *(const bf16x8*)&smA[(r * 16 + mr) * 64 + ((q2 ^ sw) << 3)];
            #pragma unroll
            for (int c = 0; c < 2; ++c)
                bf[c] = *(const bf16x8*)&smB[(wave * 32 + c * 16 + mr) * 64 + ((q2 ^ sw) << 3)];
            #pragma unroll
            for (int r = 0; r < 4; ++r)
                #pragma unroll
                for (int c = 0; c < 2; ++c)
                    acc[r][c] = __builtin_amdgcn_mfma_f32_16x16x32_bf16(af[r], bf[c], acc[r][c], 0, 0, 0);
        }
        __syncthreads();
    }

    #pragma unroll
    for (int r = 0; r < 4; ++r)
        #pragma unroll
        for (int c = 0; c < 2; ++c) {
            const int col = n0 + wave * 32 + c * 16 + mr;
            #pragma unroll
            for (int e = 0; e < 4; ++e) {
                const int rowg = m0 + r * 16 + quad * 4 + e;
                Og[(long)zz * LC + (long)rowg * 512 + col] = f2bf(acc[r][c][e]);
            }
        }
}

// ---------------------------------------------------------------------------
// Final projection: out(fp32) = O @ Wo^T + bo. 64x128 tile (R8 config).
__global__ __launch_bounds__(256)
void oproj_gemm(const unsigned short* __restrict__ Ag, const unsigned short* __restrict__ Bg,
                float* __restrict__ Cf, const float* __restrict__ bias)
{
    __shared__ __align__(16) unsigned short smA[64 * 64];
    __shared__ __align__(16) unsigned short smB[128 * 64];

    int mt, nt, zz;
    tile_decode<false>(blockIdx.x, 4, 128, 16, mt, nt, zz);
    (void)zz;

    const int tid = threadIdx.x;
    const int m0 = mt * 64, n0 = nt * 128;
    const unsigned short* pA = Ag + (long)m0 * 512;
    const unsigned short* pB = Bg + (long)n0 * 512;

    const int wave = tid >> 6, lane = tid & 63;
    const int quad = lane >> 4, mr = lane & 15;
    const int sw = mr & 7;

    f32x4 acc[4][2] = {};

    for (int k0 = 0; k0 < 512; k0 += 64) {
        stage64<64>(pA + k0, 512, smA, wave, lane);
        stage64<128>(pB + k0, 512, smB, wave, lane);
        __syncthreads();
        #pragma unroll
        for (int h = 0; h < 2; ++h) {
            const int q2 = (h << 2) | quad;
            bf16x8 af[4], bf[2];
            #pragma unroll
            for (int r = 0; r < 4; ++r)
                af[r] = *(const bf16x8*)&smA[(r * 16 + mr) * 64 + ((q2 ^ sw) << 3)];
            #pragma unroll
            for (int c = 0; c < 2; ++c)
                bf[c] = *(const bf16x8*)&smB[(wave * 32 + c * 16 + mr) * 64 + ((q2 ^ sw) << 3)];
            #pragma unroll
            for (int r = 0; r < 4; ++r)
                #pragma unroll
                for (int c = 0; c < 2; ++c)
                    acc[r][c] = __builtin_amdgcn_mfma_f32_16x16x32_bf16(af[r], bf[c], acc[r][c], 0, 0, 0);
        }
        __syncthreads();
    }

    #pragma unroll
    for (int r = 0; r < 4; ++r)
        #pragma unroll
        for (int c = 0; c < 2; ++c) {
            const int col = n0 + wave * 32 + c * 16 + mr;
            const float bv = bias[col];
            #pragma unroll
            for (int e = 0; e < 4; ++e) {
                const int rowg = m0 + r * 16 + quad * 4 + e;
                Cf[(long)rowg * 512 + col] = acc[r][c][e] + bv;
            }
        }
}

// ---------------------------------------------------------------------------
extern "C" void kernel_launch(void* const* d_in, const int* in_sizes, int n_in,
                              void* d_out, int out_size, void* d_ws, size_t ws_size,
                              hipStream_t stream) {
    const float* query = (const float*)d_in[0];
    const float* key   = (const float*)d_in[1];
    const float* value = (const float*)d_in[2];
    const float* Wq    = (const float*)d_in[3];
    const float* bq    = (const float*)d_in[4];
    const float* Wk    = (const float*)d_in[5];
    const float* bk    = (const float*)d_in[6];
    const float* Wv    = (const float*)d_in[7];
    const float* bv    = (const float*)d_in[8];
    const float* Wo    = (const float*)d_in[9];
    const float* bo    = (const float*)d_in[10];
    float* out = (float*)d_out;

    const int B = 4, L = 2048, C = 512;
    char* ws = (char*)d_ws;

    // ---- workspace map (bytes), total ~70.2 MB ----------------------------
    unsigned short* WqT_h = (unsigned short*)(ws);
    unsigned short* WkT_h = (unsigned short*)(ws + 524288);
    unsigned short* WvT_h = (unsigned short*)(ws + 1048576);
    unsigned short* WoT_h = (unsigned short*)(ws + 1572864);
    unsigned short* Q_h   = (unsigned short*)(ws + 2097152);
    unsigned short* K_h   = (unsigned short*)(ws + 10485760);
    unsigned short* VT_h  = (unsigned short*)(ws + 18874368);
    unsigned short* S     = (unsigned short*)(ws + 27262976);
    float2*         stats = (float2*)(ws + 60817408);
    unsigned short* O_h   = (unsigned short*)(ws + 61865984);

    const dim3 blk(256);
    const float scale = 1.0f / sqrtf((float)C);

    // 1) weight transposes -> bf16
    WT4Args wt;
    wt.src[0] = Wq; wt.src[1] = Wk; wt.src[2] = Wv; wt.src[3] = Wo;
    wt.dh[0] = WqT_h; wt.dh[1] = WkT_h; wt.dh[2] = WvT_h; wt.dh[3] = WoT_h;
    wtrans4<<<dim3(16, 16, 4), blk, 0, stream>>>(wt);

    // 2) merged projections, register-direct barrier-free (768 blocks)
    ProjArgs pa;
    pa.Af[0] = query; pa.Bh[0] = WqT_h; pa.bias[0] = bq; pa.Ch[0] = Q_h;
    pa.Af[1] = key;   pa.Bh[1] = WkT_h; pa.bias[1] = bk; pa.Ch[1] = K_h;
    pa.Af[2] = value; pa.Bh[2] = WvT_h; pa.bias[2] = bv; pa.Ch[2] = VT_h;
    proj_gemm<<<dim3(768), blk, 0, stream>>>(pa);

    // 3) S = scale * Q @ K^T -> fp16 + partial stats (1024 blocks)
    qkt_gemm<<<dim3(1024), blk, 0, stream>>>(Q_h, K_h, S, stats, scale);

    // 4) O = softmax(S) @ V -> bf16, 64x128 tiles (512 blocks)
    pv_gemm<<<dim3(512), blk, 0, stream>>>(S, VT_h, stats, O_h);

    // 5) out = O @ Wo^T + bo, 64x128 tiles (512 blocks)
    oproj_gemm<<<dim3(512), blk, 0, stream>>>(O_h, WoT_h, out, bo);
}

// Round 12
// 225.140 us; speedup vs baseline: 1.1036x; 1.1036x over previous
//
#include <hip/hip_runtime.h>
#include <hip/hip_fp16.h>
#include <hip/hip_bf16.h>
#include <math.h>

typedef __attribute__((ext_vector_type(8))) short bf16x8;
typedef __attribute__((ext_vector_type(4))) float f32x4;

__device__ __forceinline__ unsigned short f2bf(float x) {
    union { float f; unsigned u; } v; v.f = x;
    unsigned r = v.u + 0x7FFFu + ((v.u >> 16) & 1u);   // RNE
    return (unsigned short)(r >> 16);
}
__device__ __forceinline__ unsigned short f2h(float x) {
    union { __half h; unsigned short u; } v; v.h = __float2half(x); return v.u;
}
__device__ __forceinline__ float h2f(unsigned short u) {
    union { __half h; unsigned short u; } v; v.u = u; return __half2float(v.h);
}
__device__ __forceinline__ float bf2f(unsigned short h) {
    union { float f; unsigned u; } v; v.u = ((unsigned)h) << 16; return v.f;
}
// pack 8 fp32 -> bf16x8 (RNE, HW packed cvt)
__device__ __forceinline__ bf16x8 pack8(const float* p) {
    union { bf16x8 v; __hip_bfloat162 b[4]; } u;
    #pragma unroll
    for (int i = 0; i < 4; ++i)
        u.b[i] = __float22bfloat162_rn(make_float2(p[2 * i], p[2 * i + 1]));
    return u.v;
}

// XCD-aware tile decode (R4-verified).
template<bool M_INNER>
__device__ __forceinline__ void tile_decode(int id, int NT, int MT, int ML,
                                            int& m, int& n, int& zz)
{
    const int xcd = id & 7;
    const int s = id >> 3;
    int mloc;
    if (M_INNER) { mloc = s % ML; n = s / ML; }
    else         { n = s % NT;   mloc = s / NT; }
    const int g = xcd * ML + mloc;
    m = g % MT;
    zz = g / MT;
}

// Async global->LDS staging of a ROWSx64 bf16 tile, 16B DMA, XOR-swizzled.
template<int ROWS>
__device__ __forceinline__ void stage64(const unsigned short* g, long lda,
                                        unsigned short* lds, int wave, int lane)
{
    const int rr = lane >> 3, cc = lane & 7;
    const int ccg = (cc ^ rr) * 8;
    #pragma unroll
    for (int s = 0; s < ROWS / 32; ++s) {
        const int seg = wave * (ROWS / 32) + s;
        const unsigned short* gp = g + (long)(seg * 8 + rr) * lda + ccg;
        __builtin_amdgcn_global_load_lds(
            (const __attribute__((address_space(1))) void*)gp,
            (__attribute__((address_space(3))) void*)(lds + seg * 512),
            16, 0, 0);
    }
}

// ---------------------------------------------------------------------------
// 4 weights [512][512] fp32 -> transposed bf16, one dispatch.
struct WT4Args {
    const float* src[4];
    unsigned short* dh[4];
};
__global__ __launch_bounds__(256)
void wtrans4(WT4Args a)
{
    __shared__ float T[32][33];
    const int z = blockIdx.z;
    const int Cc = 512, R = 512;
    const float* s = a.src[z];
    const int r0 = blockIdx.y * 32, c0 = blockIdx.x * 32;
    const int t = threadIdx.x;
    {
        const int r = t >> 3, cq = (t & 7) * 4;
        float4 v = *(const float4*)(s + (long)(r0 + r) * Cc + c0 + cq);
        T[r][cq] = v.x; T[r][cq + 1] = v.y; T[r][cq + 2] = v.z; T[r][cq + 3] = v.w;
    }
    __syncthreads();
    {
        const int c = t >> 3, rq = (t & 7) * 4;
        ushort4 h;
        h.x = f2bf(T[rq][c]); h.y = f2bf(T[rq + 1][c]);
        h.z = f2bf(T[rq + 2][c]); h.w = f2bf(T[rq + 3][c]);
        *(ushort4*)(a.dh[z] + (long)(c0 + c) * R + r0 + rq) = h;
    }
}

// ---------------------------------------------------------------------------
// Merged Q/K/V projection, 128x128 tile, BK=64 (R8 best-measured config).
// A: fp32 fused cvt, pipelined VGPR staging, XOR LDS. B: DMA.
struct ProjArgs {
    const float* Af[3];
    const unsigned short* Bh[3];
    const float* bias[3];
    unsigned short* Ch[3];
};
__global__ __launch_bounds__(256)
void proj_gemm(ProjArgs pa)
{
    __shared__ __align__(16) unsigned short smA[128 * 64];
    __shared__ __align__(16) unsigned short smB[128 * 64];

    int mt, nt, z;
    tile_decode<false>(blockIdx.x, 4, 64, 24, mt, nt, z);

    const float* pAf = pa.Af[z] + (long)(mt * 128) * 512;
    const unsigned short* pBh = pa.Bh[z] + (long)(nt * 128) * 512;
    const float* bias = pa.bias[z];

    const int tid = threadIdx.x;
    const int m0 = mt * 128, n0 = nt * 128;
    const int wave = tid >> 6, lane = tid & 63;
    const int wr = wave >> 1, wc = wave & 1;
    const int quad = lane >> 4, mr = lane & 15;
    const int sw = mr & 7;
    const int tr = tid >> 1, hf = tid & 1;   // A staging: row, 32-float half
    const int swA = tr & 7;

    f32x4 acc[4][4] = {};

    float4 pre[8];
    {
        const float* s0 = pAf + (long)tr * 512 + hf * 32;
        #pragma unroll
        for (int jj = 0; jj < 8; ++jj) pre[jj] = *(const float4*)(s0 + jj * 4);
    }

    for (int k0 = 0; k0 < 512; k0 += 64) {
        #pragma unroll
        for (int jj = 0; jj < 4; ++jj) {
            float t[8] = { pre[2 * jj].x, pre[2 * jj].y, pre[2 * jj].z, pre[2 * jj].w,
                           pre[2 * jj + 1].x, pre[2 * jj + 1].y, pre[2 * jj + 1].z, pre[2 * jj + 1].w };
            const int cc = hf * 4 + jj;
            *(bf16x8*)&smA[tr * 64 + ((cc ^ swA) << 3)] = pack8(t);
        }
        stage64<128>(pBh + k0, 512, smB, wave, lane);
        __syncthreads();

        if (k0 + 64 < 512) {
            const float* s2 = pAf + (long)tr * 512 + (k0 + 64) + hf * 32;
            #pragma unroll
            for (int jj = 0; jj < 8; ++jj) pre[jj] = *(const float4*)(s2 + jj * 4);
        }

        #pragma unroll
        for (int h = 0; h < 2; ++h) {
            const int q2 = (h << 2) | quad;
            bf16x8 af[4], bf[4];
            #pragma unroll
            for (int r = 0; r < 4; ++r)
                af[r] = *(const bf16x8*)&smA[(wr * 64 + r * 16 + mr) * 64 + ((q2 ^ sw) << 3)];
            #pragma unroll
            for (int c = 0; c < 4; ++c)
                bf[c] = *(const bf16x8*)&smB[(wc * 64 + c * 16 + mr) * 64 + ((q2 ^ sw) << 3)];
            #pragma unroll
            for (int r = 0; r < 4; ++r)
                #pragma unroll
                for (int c = 0; c < 4; ++c)
                    acc[r][c] = __builtin_amdgcn_mfma_f32_16x16x32_bf16(af[r], bf[c], acc[r][c], 0, 0, 0);
        }
        __syncthreads();
    }

    if (z < 2) {
        unsigned short* Chi = pa.Ch[z];
        #pragma unroll
        for (int r = 0; r < 4; ++r)
            #pragma unroll
            for (int c = 0; c < 4; ++c) {
                const int col = n0 + wc * 64 + c * 16 + mr;
                const float bv = bias[col];
                #pragma unroll
                for (int e = 0; e < 4; ++e) {
                    const int rowg = m0 + wr * 64 + r * 16 + quad * 4 + e;
                    Chi[(long)rowg * 512 + col] = f2bf(acc[r][c][e] + bv);
                }
            }
    } else {
        // transposed: VT[b][col][l]
        unsigned short* VTh = pa.Ch[2];
        #pragma unroll
        for (int r = 0; r < 4; ++r)
            #pragma unroll
            for (int c = 0; c < 4; ++c) {
                const int col = n0 + wc * 64 + c * 16 + mr;
                const float bv = bias[col];
                const int rowg0 = m0 + wr * 64 + r * 16 + quad * 4;
                const int b = rowg0 >> 11, l0 = rowg0 & 2047;
                ushort4 hv;
                hv.x = f2bf(acc[r][c][0] + bv);
                hv.y = f2bf(acc[r][c][1] + bv);
                hv.z = f2bf(acc[r][c][2] + bv);
                hv.w = f2bf(acc[r][c][3] + bv);
                *(ushort4*)(VTh + (long)b * (512 * 2048) + (long)col * 2048 + l0) = hv;
            }
    }
}

// ---------------------------------------------------------------------------
// QK^T: P-partial(bf16) = exp(scale*QK^T - m_tile), plus per-(row, n-tile)
// stats (m_tile, sum_exp). 128x128 tile, BK=64, swizzled staging.
union QKTSmem {
    unsigned short stage[2][128 * 64];
    unsigned short ep[128 * 132];
};
__global__ __launch_bounds__(256)
void qkt_gemm(const unsigned short* __restrict__ Qg, const unsigned short* __restrict__ Kg,
              unsigned short* __restrict__ Sg, float2* __restrict__ stats, float alpha)
{
    __shared__ __align__(16) QKTSmem sm;

    int mt, nt, zz;
    tile_decode<true>(blockIdx.x, 16, 16, 8, mt, nt, zz);

    const int tid = threadIdx.x;
    const int m0 = mt * 128, n0 = nt * 128;
    const long LC = 2048L * 512;
    const unsigned short* pA = Qg + (long)zz * LC + (long)m0 * 512;
    const unsigned short* pB = Kg + (long)zz * LC + (long)n0 * 512;

    const int wave = tid >> 6, lane = tid & 63;
    const int wr = wave >> 1, wc = wave & 1;
    const int quad = lane >> 4, mr = lane & 15;
    const int sw = mr & 7;

    f32x4 acc[4][4] = {};

    for (int k0 = 0; k0 < 512; k0 += 64) {
        stage64<128>(pA + k0, 512, sm.stage[0], wave, lane);
        stage64<128>(pB + k0, 512, sm.stage[1], wave, lane);
        __syncthreads();
        #pragma unroll
        for (int h = 0; h < 2; ++h) {
            const int q2 = (h << 2) | quad;
            bf16x8 af[4], bf[4];
            #pragma unroll
            for (int r = 0; r < 4; ++r)
                af[r] = *(const bf16x8*)&sm.stage[0][(wr * 64 + r * 16 + mr) * 64 + ((q2 ^ sw) << 3)];
            #pragma unroll
            for (int c = 0; c < 4; ++c)
                bf[c] = *(const bf16x8*)&sm.stage[1][(wc * 64 + c * 16 + mr) * 64 + ((q2 ^ sw) << 3)];
            #pragma unroll
            for (int r = 0; r < 4; ++r)
                #pragma unroll
                for (int c = 0; c < 4; ++c)
                    acc[r][c] = __builtin_amdgcn_mfma_f32_16x16x32_bf16(af[r], bf[c], acc[r][c], 0, 0, 0);
        }
        __syncthreads();
    }

    // epilogue: acc -> LDS fp16 s (transposed) -> exp + coalesced bf16 stores
    #pragma unroll
    for (int r = 0; r < 4; ++r)
        #pragma unroll
        for (int c = 0; c < 4; ++c) {
            const int col = wc * 64 + c * 16 + mr;
            #pragma unroll
            for (int e = 0; e < 4; ++e) {
                const int rowl = wr * 64 + r * 16 + quad * 4 + e;
                sm.ep[rowl * 132 + col] = f2h(acc[r][c][e] * alpha);
            }
        }
    __syncthreads();
    {
        const int R = tid >> 1, hh = tid & 1;
        const unsigned short* src = &sm.ep[R * 132 + hh * 64];
        unsigned short* dst = Sg + (long)zz * (2048L * 2048) + (long)(m0 + R) * 2048 + n0 + hh * 64;
        bf16x8 ch[8];
        #pragma unroll
        for (int j = 0; j < 8; ++j) ch[j] = *(const bf16x8*)(src + j * 8);
        float mloc = -1e30f;
        #pragma unroll
        for (int j = 0; j < 8; ++j)
            #pragma unroll
            for (int i = 0; i < 8; ++i)
                mloc = fmaxf(mloc, h2f((unsigned short)ch[j][i]));
        const float m2 = fmaxf(mloc, __shfl_xor(mloc, 1));
        float sl = 0.f;
        #pragma unroll
        for (int j = 0; j < 8; ++j) {
            float t[8];
            #pragma unroll
            for (int i = 0; i < 8; ++i) {
                t[i] = __expf(h2f((unsigned short)ch[j][i]) - m2);
                sl += t[i];
            }
            *(bf16x8*)(dst + j * 8) = pack8(t);
        }
        sl += __shfl_xor(sl, 1);
        if (hh == 0)
            stats[((long)zz * 2048 + m0 + R) * 16 + nt] = make_float2(m2, sl);
    }
}

// ---------------------------------------------------------------------------
// PV with fused softmax finalization: O(bf16) = softmax(S) @ V.
// S holds bf16 exp(s - m_tile); staging scales by exp(m_tile - m_row)/l_row
// (one 8B stats load + one exp per 64-k chunk). 64x128 tile (R8 config).
__global__ __launch_bounds__(256)
void pv_gemm(const unsigned short* __restrict__ Sg, const unsigned short* __restrict__ VTg,
             const float2* __restrict__ stats, unsigned short* __restrict__ Og)
{
    __shared__ __align__(16) unsigned short smA[64 * 64];
    __shared__ __align__(16) unsigned short smB[128 * 64];

    int mt, nt, zz;
    tile_decode<false>(blockIdx.x, 4, 32, 16, mt, nt, zz);

    const int tid = threadIdx.x;
    const int m0 = mt * 64, n0 = nt * 128;
    const long LL = 2048L * 2048, LC = 2048L * 512;
    const unsigned short* pS = Sg + (long)zz * LL + (long)m0 * 2048;
    const unsigned short* pB = VTg + (long)zz * LC + (long)n0 * 2048;

    const int wave = tid >> 6, lane = tid & 63;
    const int quad = lane >> 4, mr = lane & 15;
    const int sw = mr & 7;
    const int tr = tid >> 2, qt = tid & 3;
    const int swA = tr & 7;

    const float2* strow = stats + ((long)zz * 2048 + m0 + tr) * 16;
    float m_row, inv_row;
    {
        float2 s[16];
        float m = -1e30f;
        #pragma unroll
        for (int i = 0; i < 16; ++i) { s[i] = strow[i]; m = fmaxf(m, s[i].x); }
        float l = 0.f;
        #pragma unroll
        for (int i = 0; i < 16; ++i) l += s[i].y * __expf(s[i].x - m);
        m_row = m;
        inv_row = 1.0f / l;
    }

    f32x4 acc[4][2] = {};

    bf16x8 pre[2];
    {
        const unsigned short* s0 = pS + (long)tr * 2048 + qt * 16;
        pre[0] = *(const bf16x8*)(s0);
        pre[1] = *(const bf16x8*)(s0 + 8);
    }

    for (int k0 = 0; k0 < 2048; k0 += 64) {
        // per-tile correction factor (re-read from L2 to avoid dyn reg index)
        const float2 sv = strow[k0 >> 7];
        const float fac = __expf(sv.x - m_row) * inv_row;
        #pragma unroll
        for (int c2 = 0; c2 < 2; ++c2) {
            float t[8];
            #pragma unroll
            for (int i = 0; i < 8; ++i)
                t[i] = bf2f((unsigned short)pre[c2][i]) * fac;
            const int cc = qt * 2 + c2;
            *(bf16x8*)&smA[tr * 64 + ((cc ^ swA) << 3)] = pack8(t);
        }
        stage64<128>(pB + k0, 2048, smB, wave, lane);
        __syncthreads();

        if (k0 + 64 < 2048) {
            const unsigned short* s2 = pS + (long)tr * 2048 + (k0 + 64) + qt * 16;
            pre[0] = *(const bf16x8*)(s2);
            pre[1] = *(const bf16x8*)(s2 + 8);
        }

        #pragma unroll
        for (int h = 0; h < 2; ++h) {
            const int q2 = (h << 2) | quad;
            bf16x8 af[4], bf[2];
            #pragma unroll
            for (int r = 0; r < 4; ++r)
                af[r] = *(const bf16x8*)&smA[(r * 16 + mr) * 64 + ((q2 ^ sw) << 3)];
            #pragma unroll
            for (int c = 0; c < 2; ++c)
                bf[c] = *(const bf16x8*)&smB[(wave * 32 + c * 16 + mr) * 64 + ((q2 ^ sw) << 3)];
            #pragma unroll
            for (int r = 0; r < 4; ++r)
                #pragma unroll
                for (int c = 0; c < 2; ++c)
                    acc[r][c] = __builtin_amdgcn_mfma_f32_16x16x32_bf16(af[r], bf[c], acc[r][c], 0, 0, 0);
        }
        __syncthreads();
    }

    #pragma unroll
    for (int r = 0; r < 4; ++r)
        #pragma unroll
        for (int c = 0; c < 2; ++c) {
            const int col = n0 + wave * 32 + c * 16 + mr;
            #pragma unroll
            for (int e = 0; e < 4; ++e) {
                const int rowg = m0 + r * 16 + quad * 4 + e;
                Og[(long)zz * LC + (long)rowg * 512 + col] = f2bf(acc[r][c][e]);
            }
        }
}

// ---------------------------------------------------------------------------
// Final projection: out(fp32) = O @ Wo^T + bo. 64x128 tile (R8 config).
__global__ __launch_bounds__(256)
void oproj_gemm(const unsigned short* __restrict__ Ag, const unsigned short* __restrict__ Bg,
                float* __restrict__ Cf, const float* __restrict__ bias)
{
    __shared__ __align__(16) unsigned short smA[64 * 64];
    __shared__ __align__(16) unsigned short smB[128 * 64];

    int mt, nt, zz;
    tile_decode<false>(blockIdx.x, 4, 128, 16, mt, nt, zz);
    (void)zz;

    const int tid = threadIdx.x;
    const int m0 = mt * 64, n0 = nt * 128;
    const unsigned short* pA = Ag + (long)m0 * 512;
    const unsigned short* pB = Bg + (long)n0 * 512;

    const int wave = tid >> 6, lane = tid & 63;
    const int quad = lane >> 4, mr = lane & 15;
    const int sw = mr & 7;

    f32x4 acc[4][2] = {};

    for (int k0 = 0; k0 < 512; k0 += 64) {
        stage64<64>(pA + k0, 512, smA, wave, lane);
        stage64<128>(pB + k0, 512, smB, wave, lane);
        __syncthreads();
        #pragma unroll
        for (int h = 0; h < 2; ++h) {
            const int q2 = (h << 2) | quad;
            bf16x8 af[4], bf[2];
            #pragma unroll
            for (int r = 0; r < 4; ++r)
                af[r] = *(const bf16x8*)&smA[(r * 16 + mr) * 64 + ((q2 ^ sw) << 3)];
            #pragma unroll
            for (int c = 0; c < 2; ++c)
                bf[c] = *(const bf16x8*)&smB[(wave * 32 + c * 16 + mr) * 64 + ((q2 ^ sw) << 3)];
            #pragma unroll
            for (int r = 0; r < 4; ++r)
                #pragma unroll
                for (int c = 0; c < 2; ++c)
                    acc[r][c] = __builtin_amdgcn_mfma_f32_16x16x32_bf16(af[r], bf[c], acc[r][c], 0, 0, 0);
        }
        __syncthreads();
    }

    #pragma unroll
    for (int r = 0; r < 4; ++r)
        #pragma unroll
        for (int c = 0; c < 2; ++c) {
            const int col = n0 + wave * 32 + c * 16 + mr;
            const float bv = bias[col];
            #pragma unroll
            for (int e = 0; e < 4; ++e) {
                const int rowg = m0 + r * 16 + quad * 4 + e;
                Cf[(long)rowg * 512 + col] = acc[r][c][e] + bv;
            }
        }
}

// ---------------------------------------------------------------------------
extern "C" void kernel_launch(void* const* d_in, const int* in_sizes, int n_in,
                              void* d_out, int out_size, void* d_ws, size_t ws_size,
                              hipStream_t stream) {
    const float* query = (const float*)d_in[0];
    const float* key   = (const float*)d_in[1];
    const float* value = (const float*)d_in[2];
    const float* Wq    = (const float*)d_in[3];
    const float* bq    = (const float*)d_in[4];
    const float* Wk    = (const float*)d_in[5];
    const float* bk    = (const float*)d_in[6];
    const float* Wv    = (const float*)d_in[7];
    const float* bv    = (const float*)d_in[8];
    const float* Wo    = (const float*)d_in[9];
    const float* bo    = (const float*)d_in[10];
    float* out = (float*)d_out;

    const int B = 4, L = 2048, C = 512;
    char* ws = (char*)d_ws;

    // ---- workspace map (bytes), total ~70.2 MB ----------------------------
    unsigned short* WqT_h = (unsigned short*)(ws);
    unsigned short* WkT_h = (unsigned short*)(ws + 524288);
    unsigned short* WvT_h = (unsigned short*)(ws + 1048576);
    unsigned short* WoT_h = (unsigned short*)(ws + 1572864);
    unsigned short* Q_h   = (unsigned short*)(ws + 2097152);
    unsigned short* K_h   = (unsigned short*)(ws + 10485760);
    unsigned short* VT_h  = (unsigned short*)(ws + 18874368);
    unsigned short* S     = (unsigned short*)(ws + 27262976);
    float2*         stats = (float2*)(ws + 60817408);
    unsigned short* O_h   = (unsigned short*)(ws + 61865984);

    const dim3 blk(256);
    const float scale = 1.0f / sqrtf((float)C);

    // 1) weight transposes -> bf16
    WT4Args wt;
    wt.src[0] = Wq; wt.src[1] = Wk; wt.src[2] = Wv; wt.src[3] = Wo;
    wt.dh[0] = WqT_h; wt.dh[1] = WkT_h; wt.dh[2] = WvT_h; wt.dh[3] = WoT_h;
    wtrans4<<<dim3(16, 16, 4), blk, 0, stream>>>(wt);

    // 2) merged projections (R8 config, 768 blocks)
    ProjArgs pa;
    pa.Af[0] = query; pa.Bh[0] = WqT_h; pa.bias[0] = bq; pa.Ch[0] = Q_h;
    pa.Af[1] = key;   pa.Bh[1] = WkT_h; pa.bias[1] = bk; pa.Ch[1] = K_h;
    pa.Af[2] = value; pa.Bh[2] = WvT_h; pa.bias[2] = bv; pa.Ch[2] = VT_h;
    proj_gemm<<<dim3(768), blk, 0, stream>>>(pa);

    // 3) P-partial = exp(scale*QK^T - m_tile) bf16 + stats (1024 blocks)
    qkt_gemm<<<dim3(1024), blk, 0, stream>>>(Q_h, K_h, S, stats, scale);

    // 4) O = softmax-finalize(P) @ V -> bf16 (512 blocks)
    pv_gemm<<<dim3(512), blk, 0, stream>>>(S, VT_h, stats, O_h);

    // 5) out = O @ Wo^T + bo, fp32 (512 blocks)
    oproj_gemm<<<dim3(512), blk, 0, stream>>>(O_h, WoT_h, out, bo);
}

// Round 13
// 215.502 us; speedup vs baseline: 1.1529x; 1.0447x over previous
//
#include <hip/hip_runtime.h>
#include <hip/hip_fp16.h>
#include <hip/hip_bf16.h>
#include <math.h>

typedef __attribute__((ext_vector_type(8))) short bf16x8;
typedef __attribute__((ext_vector_type(4))) float f32x4;

__device__ __forceinline__ unsigned short f2bf(float x) {
    union { float f; unsigned u; } v; v.f = x;
    unsigned r = v.u + 0x7FFFu + ((v.u >> 16) & 1u);   // RNE
    return (unsigned short)(r >> 16);
}
__device__ __forceinline__ unsigned short f2h(float x) {
    union { __half h; unsigned short u; } v; v.h = __float2half(x); return v.u;
}
__device__ __forceinline__ float h2f(unsigned short u) {
    union { __half h; unsigned short u; } v; v.u = u; return __half2float(v.h);
}
__device__ __forceinline__ float bf2f(unsigned short h) {
    union { float f; unsigned u; } v; v.u = ((unsigned)h) << 16; return v.f;
}
// pack 8 fp32 -> bf16x8 (RNE, HW packed cvt)
__device__ __forceinline__ bf16x8 pack8(const float* p) {
    union { bf16x8 v; __hip_bfloat162 b[4]; } u;
    #pragma unroll
    for (int i = 0; i < 4; ++i)
        u.b[i] = __float22bfloat162_rn(make_float2(p[2 * i], p[2 * i + 1]));
    return u.v;
}

// XCD-aware tile decode (R4-verified).
template<bool M_INNER>
__device__ __forceinline__ void tile_decode(int id, int NT, int MT, int ML,
                                            int& m, int& n, int& zz)
{
    const int xcd = id & 7;
    const int s = id >> 3;
    int mloc;
    if (M_INNER) { mloc = s % ML; n = s / ML; }
    else         { n = s % NT;   mloc = s / NT; }
    const int g = xcd * ML + mloc;
    m = g % MT;
    zz = g / MT;
}

// Async global->LDS staging of a ROWSx64 bf16 tile, 16B DMA, XOR-swizzled.
template<int ROWS>
__device__ __forceinline__ void stage64(const unsigned short* g, long lda,
                                        unsigned short* lds, int wave, int lane)
{
    const int rr = lane >> 3, cc = lane & 7;
    const int ccg = (cc ^ rr) * 8;
    #pragma unroll
    for (int s = 0; s < ROWS / 32; ++s) {
        const int seg = wave * (ROWS / 32) + s;
        const unsigned short* gp = g + (long)(seg * 8 + rr) * lda + ccg;
        __builtin_amdgcn_global_load_lds(
            (const __attribute__((address_space(1))) void*)gp,
            (__attribute__((address_space(3))) void*)(lds + seg * 512),
            16, 0, 0);
    }
}

// Async global->LDS staging of a 128x64 FP32 tile (32 KB), 16B DMA.
// LDS row pitch = 64 fp32 (256 B = 16 chunks). Since the DMA's LDS dest is
// fixed (base + lane*16), the swizzle is applied on the GLOBAL chunk index:
// LDS slot s of row R holds global chunk s ^ (R&15). Reads of chunk pair
// (2q, 2q+1) use slots (2q)^(R&15), (2q+1)^(R&15) -> 2-way aliasing (free).
__device__ __forceinline__ void stage_f32(const float* g, long lda,
                                          float* lds, int wave, int lane)
{
    const int rr = lane >> 4;      // row within 4-row segment
    const int sc = lane & 15;      // LDS slot this lane's 16B lands in
    #pragma unroll
    for (int s = 0; s < 8; ++s) {
        const int seg = wave * 8 + s;          // 0..31, 4 rows each
        const int row = seg * 4 + rr;          // 0..127
        const int cc = (sc ^ (row & 15)) * 4;  // global fp32 offset in k-window
        const float* gp = g + (long)row * lda + cc;
        __builtin_amdgcn_global_load_lds(
            (const __attribute__((address_space(1))) void*)gp,
            (__attribute__((address_space(3))) void*)(lds + seg * 256),
            16, 0, 0);
    }
}

// ---------------------------------------------------------------------------
// 4 weights [512][512] fp32 -> transposed bf16, one dispatch.
struct WT4Args {
    const float* src[4];
    unsigned short* dh[4];
};
__global__ __launch_bounds__(256)
void wtrans4(WT4Args a)
{
    __shared__ float T[32][33];
    const int z = blockIdx.z;
    const int Cc = 512, R = 512;
    const float* s = a.src[z];
    const int r0 = blockIdx.y * 32, c0 = blockIdx.x * 32;
    const int t = threadIdx.x;
    {
        const int r = t >> 3, cq = (t & 7) * 4;
        float4 v = *(const float4*)(s + (long)(r0 + r) * Cc + c0 + cq);
        T[r][cq] = v.x; T[r][cq + 1] = v.y; T[r][cq + 2] = v.z; T[r][cq + 3] = v.w;
    }
    __syncthreads();
    {
        const int c = t >> 3, rq = (t & 7) * 4;
        ushort4 h;
        h.x = f2bf(T[rq][c]); h.y = f2bf(T[rq + 1][c]);
        h.z = f2bf(T[rq + 2][c]); h.w = f2bf(T[rq + 3][c]);
        *(ushort4*)(a.dh[z] + (long)(c0 + c) * R + r0 + rq) = h;
    }
}

// ---------------------------------------------------------------------------
// Merged Q/K/V projection, 128x128 tile, BK=64. ALL-DMA staging: A as raw
// fp32 (32 KB, global-side XOR swizzle), B as bf16 (16 KB). fp32->bf16 cvt
// happens on the LDS->fragment read. No VGPR-load dependency in the k-loop.
struct ProjArgs {
    const float* Af[3];
    const unsigned short* Bh[3];
    const float* bias[3];
    unsigned short* Ch[3];
};
__global__ __launch_bounds__(256)
void proj_gemm(ProjArgs pa)
{
    __shared__ __align__(16) float          smA32[128 * 64];   // 32 KB fp32
    __shared__ __align__(16) unsigned short smB[128 * 64];     // 16 KB bf16

    int mt, nt, z;
    tile_decode<false>(blockIdx.x, 4, 64, 24, mt, nt, z);

    const float* pAf = pa.Af[z] + (long)(mt * 128) * 512;
    const unsigned short* pBh = pa.Bh[z] + (long)(nt * 128) * 512;
    const float* bias = pa.bias[z];

    const int tid = threadIdx.x;
    const int m0 = mt * 128, n0 = nt * 128;
    const int wave = tid >> 6, lane = tid & 63;
    const int wr = wave >> 1, wc = wave & 1;
    const int quad = lane >> 4, mr = lane & 15;
    const int sw = mr & 7;

    f32x4 acc[4][4] = {};

    for (int k0 = 0; k0 < 512; k0 += 64) {
        stage_f32(pAf + k0, 512, smA32, wave, lane);
        stage64<128>(pBh + k0, 512, smB, wave, lane);
        __syncthreads();

        #pragma unroll
        for (int h = 0; h < 2; ++h) {
            const int q2 = (h << 2) | quad;
            bf16x8 af[4], bf[4];
            #pragma unroll
            for (int r = 0; r < 4; ++r) {
                const int R = wr * 64 + r * 16 + mr;
                const int s0 = (2 * q2) ^ (R & 15);
                const int s1 = (2 * q2 + 1) ^ (R & 15);
                float4 a = *(const float4*)&smA32[R * 64 + s0 * 4];
                float4 b = *(const float4*)&smA32[R * 64 + s1 * 4];
                float t[8] = { a.x, a.y, a.z, a.w, b.x, b.y, b.z, b.w };
                af[r] = pack8(t);
            }
            #pragma unroll
            for (int c = 0; c < 4; ++c)
                bf[c] = *(const bf16x8*)&smB[(wc * 64 + c * 16 + mr) * 64 + ((q2 ^ sw) << 3)];
            #pragma unroll
            for (int r = 0; r < 4; ++r)
                #pragma unroll
                for (int c = 0; c < 4; ++c)
                    acc[r][c] = __builtin_amdgcn_mfma_f32_16x16x32_bf16(af[r], bf[c], acc[r][c], 0, 0, 0);
        }
        __syncthreads();
    }

    if (z < 2) {
        unsigned short* Chi = pa.Ch[z];
        #pragma unroll
        for (int r = 0; r < 4; ++r)
            #pragma unroll
            for (int c = 0; c < 4; ++c) {
                const int col = n0 + wc * 64 + c * 16 + mr;
                const float bv = bias[col];
                #pragma unroll
                for (int e = 0; e < 4; ++e) {
                    const int rowg = m0 + wr * 64 + r * 16 + quad * 4 + e;
                    Chi[(long)rowg * 512 + col] = f2bf(acc[r][c][e] + bv);
                }
            }
    } else {
        // transposed: VT[b][col][l]
        unsigned short* VTh = pa.Ch[2];
        #pragma unroll
        for (int r = 0; r < 4; ++r)
            #pragma unroll
            for (int c = 0; c < 4; ++c) {
                const int col = n0 + wc * 64 + c * 16 + mr;
                const float bv = bias[col];
                const int rowg0 = m0 + wr * 64 + r * 16 + quad * 4;
                const int b = rowg0 >> 11, l0 = rowg0 & 2047;
                ushort4 hv;
                hv.x = f2bf(acc[r][c][0] + bv);
                hv.y = f2bf(acc[r][c][1] + bv);
                hv.z = f2bf(acc[r][c][2] + bv);
                hv.w = f2bf(acc[r][c][3] + bv);
                *(ushort4*)(VTh + (long)b * (512 * 2048) + (long)col * 2048 + l0) = hv;
            }
    }
}

// ---------------------------------------------------------------------------
// QK^T: P-partial(bf16) = exp(scale*QK^T - m_tile), plus per-(row, n-tile)
// stats (m_tile, sum_exp). 128x128 tile, BK=64, swizzled staging.
union QKTSmem {
    unsigned short stage[2][128 * 64];
    unsigned short ep[128 * 132];
};
__global__ __launch_bounds__(256)
void qkt_gemm(const unsigned short* __restrict__ Qg, const unsigned short* __restrict__ Kg,
              unsigned short* __restrict__ Sg, float2* __restrict__ stats, float alpha)
{
    __shared__ __align__(16) QKTSmem sm;

    int mt, nt, zz;
    tile_decode<true>(blockIdx.x, 16, 16, 8, mt, nt, zz);

    const int tid = threadIdx.x;
    const int m0 = mt * 128, n0 = nt * 128;
    const long LC = 2048L * 512;
    const unsigned short* pA = Qg + (long)zz * LC + (long)m0 * 512;
    const unsigned short* pB = Kg + (long)zz * LC + (long)n0 * 512;

    const int wave = tid >> 6, lane = tid & 63;
    const int wr = wave >> 1, wc = wave & 1;
    const int quad = lane >> 4, mr = lane & 15;
    const int sw = mr & 7;

    f32x4 acc[4][4] = {};

    for (int k0 = 0; k0 < 512; k0 += 64) {
        stage64<128>(pA + k0, 512, sm.stage[0], wave, lane);
        stage64<128>(pB + k0, 512, sm.stage[1], wave, lane);
        __syncthreads();
        #pragma unroll
        for (int h = 0; h < 2; ++h) {
            const int q2 = (h << 2) | quad;
            bf16x8 af[4], bf[4];
            #pragma unroll
            for (int r = 0; r < 4; ++r)
                af[r] = *(const bf16x8*)&sm.stage[0][(wr * 64 + r * 16 + mr) * 64 + ((q2 ^ sw) << 3)];
            #pragma unroll
            for (int c = 0; c < 4; ++c)
                bf[c] = *(const bf16x8*)&sm.stage[1][(wc * 64 + c * 16 + mr) * 64 + ((q2 ^ sw) << 3)];
            #pragma unroll
            for (int r = 0; r < 4; ++r)
                #pragma unroll
                for (int c = 0; c < 4; ++c)
                    acc[r][c] = __builtin_amdgcn_mfma_f32_16x16x32_bf16(af[r], bf[c], acc[r][c], 0, 0, 0);
        }
        __syncthreads();
    }

    // epilogue: acc -> LDS fp16 s (transposed) -> exp + coalesced bf16 stores
    #pragma unroll
    for (int r = 0; r < 4; ++r)
        #pragma unroll
        for (int c = 0; c < 4; ++c) {
            const int col = wc * 64 + c * 16 + mr;
            #pragma unroll
            for (int e = 0; e < 4; ++e) {
                const int rowl = wr * 64 + r * 16 + quad * 4 + e;
                sm.ep[rowl * 132 + col] = f2h(acc[r][c][e] * alpha);
            }
        }
    __syncthreads();
    {
        const int R = tid >> 1, hh = tid & 1;
        const unsigned short* src = &sm.ep[R * 132 + hh * 64];
        unsigned short* dst = Sg + (long)zz * (2048L * 2048) + (long)(m0 + R) * 2048 + n0 + hh * 64;
        bf16x8 ch[8];
        #pragma unroll
        for (int j = 0; j < 8; ++j) ch[j] = *(const bf16x8*)(src + j * 8);
        float mloc = -1e30f;
        #pragma unroll
        for (int j = 0; j < 8; ++j)
            #pragma unroll
            for (int i = 0; i < 8; ++i)
                mloc = fmaxf(mloc, h2f((unsigned short)ch[j][i]));
        const float m2 = fmaxf(mloc, __shfl_xor(mloc, 1));
        float sl = 0.f;
        #pragma unroll
        for (int j = 0; j < 8; ++j) {
            float t[8];
            #pragma unroll
            for (int i = 0; i < 8; ++i) {
                t[i] = __expf(h2f((unsigned short)ch[j][i]) - m2);
                sl += t[i];
            }
            *(bf16x8*)(dst + j * 8) = pack8(t);
        }
        sl += __shfl_xor(sl, 1);
        if (hh == 0)
            stats[((long)zz * 2048 + m0 + R) * 16 + nt] = make_float2(m2, sl);
    }
}

// ---------------------------------------------------------------------------
// PV with fused softmax finalization: O(bf16) = softmax(S) @ V.
// S holds bf16 exp(s - m_tile); staging scales by exp(m_tile - m_row)/l_row.
__global__ __launch_bounds__(256)
void pv_gemm(const unsigned short* __restrict__ Sg, const unsigned short* __restrict__ VTg,
             const float2* __restrict__ stats, unsigned short* __restrict__ Og)
{
    __shared__ __align__(16) unsigned short smA[64 * 64];
    __shared__ __align__(16) unsigned short smB[128 * 64];

    int mt, nt, zz;
    tile_decode<false>(blockIdx.x, 4, 32, 16, mt, nt, zz);

    const int tid = threadIdx.x;
    const int m0 = mt * 64, n0 = nt * 128;
    const long LL = 2048L * 2048, LC = 2048L * 512;
    const unsigned short* pS = Sg + (long)zz * LL + (long)m0 * 2048;
    const unsigned short* pB = VTg + (long)zz * LC + (long)n0 * 2048;

    const int wave = tid >> 6, lane = tid & 63;
    const int quad = lane >> 4, mr = lane & 15;
    const int sw = mr & 7;
    const int tr = tid >> 2, qt = tid & 3;
    const int swA = tr & 7;

    const float2* strow = stats + ((long)zz * 2048 + m0 + tr) * 16;
    float m_row, inv_row;
    {
        float2 s[16];
        float m = -1e30f;
        #pragma unroll
        for (int i = 0; i < 16; ++i) { s[i] = strow[i]; m = fmaxf(m, s[i].x); }
        float l = 0.f;
        #pragma unroll
        for (int i = 0; i < 16; ++i) l += s[i].y * __expf(s[i].x - m);
        m_row = m;
        inv_row = 1.0f / l;
    }

    f32x4 acc[4][2] = {};

    bf16x8 pre[2];
    {
        const unsigned short* s0 = pS + (long)tr * 2048 + qt * 16;
        pre[0] = *(const bf16x8*)(s0);
        pre[1] = *(const bf16x8*)(s0 + 8);
    }

    for (int k0 = 0; k0 < 2048; k0 += 64) {
        const float2 sv = strow[k0 >> 7];
        const float fac = __expf(sv.x - m_row) * inv_row;
        #pragma unroll
        for (int c2 = 0; c2 < 2; ++c2) {
            float t[8];
            #pragma unroll
            for (int i = 0; i < 8; ++i)
                t[i] = bf2f((unsigned short)pre[c2][i]) * fac;
            const int cc = qt * 2 + c2;
            *(bf16x8*)&smA[tr * 64 + ((cc ^ swA) << 3)] = pack8(t);
        }
        stage64<128>(pB + k0, 2048, smB, wave, lane);
        __syncthreads();

        if (k0 + 64 < 2048) {
            const unsigned short* s2 = pS + (long)tr * 2048 + (k0 + 64) + qt * 16;
            pre[0] = *(const bf16x8*)(s2);
            pre[1] = *(const bf16x8*)(s2 + 8);
        }

        #pragma unroll
        for (int h = 0; h < 2; ++h) {
            const int q2 = (h << 2) | quad;
            bf16x8 af[4], bf[2];
            #pragma unroll
            for (int r = 0; r < 4; ++r)
                af[r] = *(const bf16x8*)&smA[(r * 16 + mr) * 64 + ((q2 ^ sw) << 3)];
            #pragma unroll
            for (int c = 0; c < 2; ++c)
                bf[c] = *(const bf16x8*)&smB[(wave * 32 + c * 16 + mr) * 64 + ((q2 ^ sw) << 3)];
            #pragma unroll
            for (int r = 0; r < 4; ++r)
                #pragma unroll
                for (int c = 0; c < 2; ++c)
                    acc[r][c] = __builtin_amdgcn_mfma_f32_16x16x32_bf16(af[r], bf[c], acc[r][c], 0, 0, 0);
        }
        __syncthreads();
    }

    #pragma unroll
    for (int r = 0; r < 4; ++r)
        #pragma unroll
        for (int c = 0; c < 2; ++c) {
            const int col = n0 + wave * 32 + c * 16 + mr;
            #pragma unroll
            for (int e = 0; e < 4; ++e) {
                const int rowg = m0 + r * 16 + quad * 4 + e;
                Og[(long)zz * LC + (long)rowg * 512 + col] = f2bf(acc[r][c][e]);
            }
        }
}

// ---------------------------------------------------------------------------
// Final projection: out(fp32) = O @ Wo^T + bo. 64x128 tile, all-DMA.
__global__ __launch_bounds__(256)
void oproj_gemm(const unsigned short* __restrict__ Ag, const unsigned short* __restrict__ Bg,
                float* __restrict__ Cf, const float* __restrict__ bias)
{
    __shared__ __align__(16) unsigned short smA[64 * 64];
    __shared__ __align__(16) unsigned short smB[128 * 64];

    int mt, nt, zz;
    tile_decode<false>(blockIdx.x, 4, 128, 16, mt, nt, zz);
    (void)zz;

    const int tid = threadIdx.x;
    const int m0 = mt * 64, n0 = nt * 128;
    const unsigned short* pA = Ag + (long)m0 * 512;
    const unsigned short* pB = Bg + (long)n0 * 512;

    const int wave = tid >> 6, lane = tid & 63;
    const int quad = lane >> 4, mr = lane & 15;
    const int sw = mr & 7;

    f32x4 acc[4][2] = {};

    for (int k0 = 0; k0 < 512; k0 += 64) {
        stage64<64>(pA + k0, 512, smA, wave, lane);
        stage64<128>(pB + k0, 512, smB, wave, lane);
        __syncthreads();
        #pragma unroll
        for (int h = 0; h < 2; ++h) {
            const int q2 = (h << 2) | quad;
            bf16x8 af[4], bf[2];
            #pragma unroll
            for (int r = 0; r < 4; ++r)
                af[r] = *(const bf16x8*)&smA[(r * 16 + mr) * 64 + ((q2 ^ sw) << 3)];
            #pragma unroll
            for (int c = 0; c < 2; ++c)
                bf[c] = *(const bf16x8*)&smB[(wave * 32 + c * 16 + mr) * 64 + ((q2 ^ sw) << 3)];
            #pragma unroll
            for (int r = 0; r < 4; ++r)
                #pragma unroll
                for (int c = 0; c < 2; ++c)
                    acc[r][c] = __builtin_amdgcn_mfma_f32_16x16x32_bf16(af[r], bf[c], acc[r][c], 0, 0, 0);
        }
        __syncthreads();
    }

    #pragma unroll
    for (int r = 0; r < 4; ++r)
        #pragma unroll
        for (int c = 0; c < 2; ++c) {
            const int col = n0 + wave * 32 + c * 16 + mr;
            const float bv = bias[col];
            #pragma unroll
            for (int e = 0; e < 4; ++e) {
                const int rowg = m0 + r * 16 + quad * 4 + e;
                Cf[(long)rowg * 512 + col] = acc[r][c][e] + bv;
            }
        }
}

// ---------------------------------------------------------------------------
extern "C" void kernel_launch(void* const* d_in, const int* in_sizes, int n_in,
                              void* d_out, int out_size, void* d_ws, size_t ws_size,
                              hipStream_t stream) {
    const float* query = (const float*)d_in[0];
    const float* key   = (const float*)d_in[1];
    const float* value = (const float*)d_in[2];
    const float* Wq    = (const float*)d_in[3];
    const float* bq    = (const float*)d_in[4];
    const float* Wk    = (const float*)d_in[5];
    const float* bk    = (const float*)d_in[6];
    const float* Wv    = (const float*)d_in[7];
    const float* bv    = (const float*)d_in[8];
    const float* Wo    = (const float*)d_in[9];
    const float* bo    = (const float*)d_in[10];
    float* out = (float*)d_out;

    const int B = 4, L = 2048, C = 512;
    char* ws = (char*)d_ws;

    // ---- workspace map (bytes), total ~70.2 MB ----------------------------
    unsigned short* WqT_h = (unsigned short*)(ws);
    unsigned short* WkT_h = (unsigned short*)(ws + 524288);
    unsigned short* WvT_h = (unsigned short*)(ws + 1048576);
    unsigned short* WoT_h = (unsigned short*)(ws + 1572864);
    unsigned short* Q_h   = (unsigned short*)(ws + 2097152);
    unsigned short* K_h   = (unsigned short*)(ws + 10485760);
    unsigned short* VT_h  = (unsigned short*)(ws + 18874368);
    unsigned short* S     = (unsigned short*)(ws + 27262976);
    float2*         stats = (float2*)(ws + 60817408);
    unsigned short* O_h   = (unsigned short*)(ws + 61865984);

    const dim3 blk(256);
    const float scale = 1.0f / sqrtf((float)C);

    // 1) weight transposes -> bf16
    WT4Args wt;
    wt.src[0] = Wq; wt.src[1] = Wk; wt.src[2] = Wv; wt.src[3] = Wo;
    wt.dh[0] = WqT_h; wt.dh[1] = WkT_h; wt.dh[2] = WvT_h; wt.dh[3] = WoT_h;
    wtrans4<<<dim3(16, 16, 4), blk, 0, stream>>>(wt);

    // 2) merged projections, all-DMA fp32-A staging (768 blocks)
    ProjArgs pa;
    pa.Af[0] = query; pa.Bh[0] = WqT_h; pa.bias[0] = bq; pa.Ch[0] = Q_h;
    pa.Af[1] = key;   pa.Bh[1] = WkT_h; pa.bias[1] = bk; pa.Ch[1] = K_h;
    pa.Af[2] = value; pa.Bh[2] = WvT_h; pa.bias[2] = bv; pa.Ch[2] = VT_h;
    proj_gemm<<<dim3(768), blk, 0, stream>>>(pa);

    // 3) P-partial = exp(scale*QK^T - m_tile) bf16 + stats (1024 blocks)
    qkt_gemm<<<dim3(1024), blk, 0, stream>>>(Q_h, K_h, S, stats, scale);

    // 4) O = softmax-finalize(P) @ V -> bf16 (512 blocks)
    pv_gemm<<<dim3(512), blk, 0, stream>>>(S, VT_h, stats, O_h);

    // 5) out = O @ Wo^T + bo, fp32 (512 blocks)
    oproj_gemm<<<dim3(512), blk, 0, stream>>>(O_h, WoT_h, out, bo);
}